// Round 4
// baseline (858.878 us; speedup 1.0000x reference)
//
#include <hip/hip_runtime.h>
#include <hip/hip_bf16.h>

#define BB 2
#define TT 2048
#define CCH 1024
#define HH 16
#define HD 64
#define EE 8
#define FF 2048
#define NTOK (BB*TT)

typedef __bf16 bf16x8 __attribute__((ext_vector_type(8)));
typedef float f32x4 __attribute__((ext_vector_type(4)));
typedef unsigned int u32;
typedef const u32 __attribute__((address_space(1)))* gads;
typedef u32 __attribute__((address_space(3)))* lads;

static __device__ __forceinline__ unsigned short f2bf(float f) {
  union { float f; unsigned u; } v; v.f = f;
  unsigned u = v.u;
  u += 0x7fffu + ((u >> 16) & 1u);
  return (unsigned short)(u >> 16);
}
static __device__ __forceinline__ float bf2f(unsigned short h) {
  union { unsigned u; float f; } v; v.u = ((unsigned)h) << 16;
  return v.f;
}

// ---------------- transpose fp32 (R x C) -> bf16 (C x R), batched over z ----
__global__ __launch_bounds__(256) void k_transpose(const float* __restrict__ in,
    unsigned short* __restrict__ out, int R, int Cc) {
  __shared__ float tile[32][33];
  size_t zoff = (size_t)blockIdx.z * (size_t)R * (size_t)Cc;
  int r0 = blockIdx.y * 32, c0 = blockIdx.x * 32;
  int tx = threadIdx.x, ty = threadIdx.y;
#pragma unroll
  for (int ii = 0; ii < 4; ++ii) {
    int i = ty + ii * 8;
    tile[i][tx] = in[zoff + (size_t)(r0 + i) * Cc + c0 + tx];
  }
  __syncthreads();
#pragma unroll
  for (int ii = 0; ii < 4; ++ii) {
    int i = ty + ii * 8;
    out[zoff + (size_t)(c0 + i) * R + r0 + tx] = f2bf(tile[tx][i]);
  }
}

// ---------------- layernorm row kernel: fp32 in -> bf16 out ----------------
__global__ __launch_bounds__(256) void k_ln(const float* __restrict__ x,
    const float* __restrict__ w, unsigned short* __restrict__ out) {
  int row = blockIdx.x;
  const float* xr = x + (size_t)row * CCH;
  int tid = threadIdx.x;
  float4 v = *(const float4*)&xr[tid * 4];
  float s = v.x + v.y + v.z + v.w;
  float ss = v.x * v.x + v.y * v.y + v.z * v.z + v.w * v.w;
#pragma unroll
  for (int off = 32; off; off >>= 1) { s += __shfl_xor(s, off); ss += __shfl_xor(ss, off); }
  __shared__ float red[8];
  int wv = tid >> 6, l = tid & 63;
  if (l == 0) { red[wv] = s; red[4 + wv] = ss; }
  __syncthreads();
  s = red[0] + red[1] + red[2] + red[3];
  ss = red[4] + red[5] + red[6] + red[7];
  float mean = s * (1.f / CCH);
  float var = ss * (1.f / CCH) - mean * mean;
  float inv = rsqrtf(var + 1e-5f);
  float4 w4 = *(const float4*)&w[tid * 4];
  ushort4 o;
  o.x = f2bf((v.x - mean) * inv * w4.x);
  o.y = f2bf((v.y - mean) * inv * w4.y);
  o.z = f2bf((v.z - mean) * inv * w4.z);
  o.w = f2bf((v.w - mean) * inv * w4.w);
  *(ushort4*)&out[(size_t)row * CCH + tid * 4] = o;
}

// ---------------- 128x128 double-buffered GEMM (2-phase T3 pattern) --------
// C(MxN) = A(MxK,bf16) * BT(NxK,bf16)^T, BK=64, global_load_lds width-16,
// linear LDS [128][64] x2 buffers, 4 waves each owning 64x64 (acc[4][4]).
// Per K-step: issue 8 gload_lds into buf^1, compute 32 MFMA on buf, barrier.
// EPI 0: bf16 out (QKV)
// EPI 1: f32 out = acc + resid (attn proj + residual)
// EPI 2: grouped, A gathered via tokarr; gelu -> bf16 (MoE up)
// EPI 3: grouped, A contiguous at offs; scaled scatter f32 (MoE down)
template<int EPI>
__global__ __launch_bounds__(256, 2) void k_gemm128(
    const unsigned short* __restrict__ A, const unsigned short* __restrict__ BT,
    unsigned short* __restrict__ Cb, float* __restrict__ Cf,
    const float* __restrict__ resid, int M, int N, int K,
    const int* __restrict__ tokarr, const int* __restrict__ slotarr,
    const float* __restrict__ wgtarr, const int* __restrict__ offs,
    const int* __restrict__ counts)
{
  __shared__ __align__(16) unsigned short As[2][128 * 64];
  __shared__ __align__(16) unsigned short Bs[2][128 * 64];

  int e = 0, off = 0, cnt = M;
  if (EPI >= 2) {
    e = blockIdx.z;
    cnt = counts[e];
    off = offs[e];
    if ((int)blockIdx.x * 128 >= cnt) return;
  }
  int m0 = blockIdx.x * 128, n0 = blockIdx.y * 128;

  int tid = threadIdx.x, l = tid & 63, w = tid >> 6;
  // staging: instruction j = w*4+i covers LDS bytes [j*1024, +1024);
  // lane l supplies row j*8 + (l>>3), elements (l&7)*8 .. +8
  int scol = (l & 7) * 8;
  const unsigned short* aptr[4];
  const unsigned short* bptr[4];
  const unsigned short* bbase = BT + (size_t)e * (size_t)N * K;
#pragma unroll
  for (int i = 0; i < 4; ++i) {
    int row = (w * 4 + i) * 8 + (l >> 3);
    int ra;
    if (EPI == 2)      ra = tokarr[off + min(m0 + row, cnt - 1)];
    else if (EPI == 3) ra = off + min(m0 + row, cnt - 1);
    else               ra = m0 + row;
    aptr[i] = A + (size_t)ra * K + scol;
    bptr[i] = bbase + (size_t)(n0 + row) * K + scol;
  }

  int wr = (w >> 1) * 64, wc = (w & 1) * 64;
  int frow = l & 15, fk = (l >> 4) * 8;
  f32x4 acc[4][4] = {};

#define STAGE(buf, k0)                                                        \
  {                                                                           \
    _Pragma("unroll")                                                         \
    for (int i = 0; i < 4; ++i) {                                             \
      int j = w * 4 + i;                                                      \
      __builtin_amdgcn_global_load_lds((gads)(const void*)(aptr[i] + (k0)),   \
                                       (lads)(void*)&As[buf][j * 512], 16, 0, 0); \
      __builtin_amdgcn_global_load_lds((gads)(const void*)(bptr[i] + (k0)),   \
                                       (lads)(void*)&Bs[buf][j * 512], 16, 0, 0); \
    }                                                                         \
  }

#define COMPUTE(buf)                                                          \
  {                                                                           \
    _Pragma("unroll")                                                         \
    for (int kk = 0; kk < 2; ++kk) {                                          \
      bf16x8 af[4], bfr[4];                                                   \
      _Pragma("unroll")                                                       \
      for (int mi = 0; mi < 4; ++mi)                                          \
        af[mi] = *(const bf16x8*)&As[buf][(wr + mi * 16 + frow) * 64 + kk * 32 + fk]; \
      _Pragma("unroll")                                                       \
      for (int ni = 0; ni < 4; ++ni)                                          \
        bfr[ni] = *(const bf16x8*)&Bs[buf][(wc + ni * 16 + frow) * 64 + kk * 32 + fk]; \
      _Pragma("unroll")                                                       \
      for (int mi = 0; mi < 4; ++mi)                                          \
        _Pragma("unroll")                                                     \
        for (int ni = 0; ni < 4; ++ni)                                        \
          acc[mi][ni] = __builtin_amdgcn_mfma_f32_16x16x32_bf16(af[mi], bfr[ni], \
                                                                acc[mi][ni], 0, 0, 0); \
    }                                                                         \
  }

  int nt = K / 64;  // tiles (16 or 32, always even here)
  STAGE(0, 0);
  __syncthreads();
  for (int t = 0; t + 2 < nt; t += 2) {
    STAGE(1, (t + 1) * 64);
    COMPUTE(0);
    __syncthreads();
    STAGE(0, (t + 2) * 64);
    COMPUTE(1);
    __syncthreads();
  }
  STAGE(1, (nt - 1) * 64);
  COMPUTE(0);
  __syncthreads();
  COMPUTE(1);

#undef STAGE
#undef COMPUTE

  int g4 = (l >> 4) * 4, cl = l & 15;
#pragma unroll
  for (int mi = 0; mi < 4; ++mi) {
#pragma unroll
    for (int r = 0; r < 4; ++r) {
      int grow = m0 + wr + mi * 16 + g4 + r;
      if (EPI >= 2 && grow >= cnt) continue;
      int tok = 0, slot = 0; float wg = 0.f;
      if (EPI == 3) {
        int fl = off + grow;
        tok = tokarr[fl]; slot = slotarr[fl]; wg = wgtarr[fl];
      }
#pragma unroll
      for (int ni = 0; ni < 4; ++ni) {
        int gcol = n0 + wc + ni * 16 + cl;
        float v = acc[mi][ni][r];
        if (EPI == 0) {
          Cb[(size_t)grow * N + gcol] = f2bf(v);
        } else if (EPI == 1) {
          Cf[(size_t)grow * N + gcol] = v + resid[(size_t)grow * N + gcol];
        } else if (EPI == 2) {
          float g = 0.5f * v * (1.f + erff(v * 0.70710678118654752f));
          Cb[(size_t)(off + grow) * N + gcol] = f2bf(g);
        } else {
          Cf[((size_t)tok * 2 + slot) * N + gcol] = wg * v;
        }
      }
    }
  }
}

// ---------------- MFMA flash attention ------------------------------------
__global__ __launch_bounds__(256) void k_attn_mfma(const unsigned short* __restrict__ qkv,
    unsigned short* __restrict__ yout)
{
  int bx = blockIdx.x, h = blockIdx.y, b = blockIdx.z;
  int tid = threadIdx.x, l = tid & 63, w = tid >> 6;
  const size_t rs = 3 * CCH;
  const int NTILE = TT / 64;  // 32

  __shared__ __align__(16) unsigned short Ks[64][72];
  __shared__ __align__(16) unsigned short Vt[64][72];
  __shared__ __align__(16) unsigned short Ps[4][16][72];

  int frow = l & 15, fk = (l >> 4) * 8;
  int g4 = l >> 4;
  int kr = tid >> 2, kc0 = (tid & 3) * 8;
  int vr = tid >> 2, vc0 = (tid & 3) * 16;

  for (int half = 0; half < 2; ++half) {
    int qt = half ? (NTILE - 1 - bx) : bx;
    int q0 = qt * 64;

    const unsigned short* qp = qkv + (size_t)((size_t)b * TT + q0 + w * 16 + frow) * rs + h * HD;
    bf16x8 qf0 = *(const bf16x8*)&qp[fk];
    bf16x8 qf1 = *(const bf16x8*)&qp[32 + fk];

    f32x4 oacc[4] = {};
    float mrow[4] = {-INFINITY, -INFINITY, -INFINITY, -INFINITY};
    float lrow[4] = {};

    for (int kb = 0; kb <= qt; ++kb) {
      int k0 = kb * 64;
      __syncthreads();
      const unsigned short* kp = qkv + (size_t)((size_t)b * TT + k0 + kr) * rs + CCH + h * HD;
      *(uint4*)&Ks[kr][kc0]      = *(const uint4*)&kp[kc0];
      *(uint4*)&Ks[kr][kc0 + 32] = *(const uint4*)&kp[kc0 + 32];
      const unsigned short* vp = qkv + (size_t)((size_t)b * TT + k0 + vr) * rs + 2 * CCH + h * HD + vc0;
      uint4 v0 = *(const uint4*)&vp[0];
      uint4 v1 = *(const uint4*)&vp[8];
      unsigned short tmp[16];
      *(uint4*)&tmp[0] = v0; *(uint4*)&tmp[8] = v1;
#pragma unroll
      for (int j = 0; j < 16; ++j) Vt[vc0 + j][vr] = tmp[j];
      __syncthreads();

      f32x4 sacc[4] = {};
#pragma unroll
      for (int nb = 0; nb < 4; ++nb) {
        bf16x8 kf0 = *(const bf16x8*)&Ks[nb * 16 + frow][fk];
        bf16x8 kf1 = *(const bf16x8*)&Ks[nb * 16 + frow][32 + fk];
        sacc[nb] = __builtin_amdgcn_mfma_f32_16x16x32_bf16(qf0, kf0, sacc[nb], 0, 0, 0);
        sacc[nb] = __builtin_amdgcn_mfma_f32_16x16x32_bf16(qf1, kf1, sacc[nb], 0, 0, 0);
      }

      bool diag = (kb == qt);
      float sv[4][4];
#pragma unroll
      for (int nb = 0; nb < 4; ++nb)
#pragma unroll
        for (int r = 0; r < 4; ++r) {
          float v = sacc[nb][r] * 0.125f;
          if (diag) {
            int ckv = nb * 16 + frow;
            int rq = w * 16 + 4 * g4 + r;
            if (ckv > rq) v = -INFINITY;
          }
          sv[nb][r] = v;
        }
      float fscale[4];
#pragma unroll
      for (int r = 0; r < 4; ++r) {
        float vm = fmaxf(fmaxf(sv[0][r], sv[1][r]), fmaxf(sv[2][r], sv[3][r]));
        vm = fmaxf(vm, __shfl_xor(vm, 1));
        vm = fmaxf(vm, __shfl_xor(vm, 2));
        vm = fmaxf(vm, __shfl_xor(vm, 4));
        vm = fmaxf(vm, __shfl_xor(vm, 8));
        float mnew = fmaxf(mrow[r], vm);
        float f = __expf(mrow[r] - mnew);
        mrow[r] = mnew;
        fscale[r] = f;
        float psum = 0.f;
#pragma unroll
        for (int nb = 0; nb < 4; ++nb) {
          float p = __expf(sv[nb][r] - mnew);
          sv[nb][r] = p;
          psum += p;
        }
        psum += __shfl_xor(psum, 1);
        psum += __shfl_xor(psum, 2);
        psum += __shfl_xor(psum, 4);
        psum += __shfl_xor(psum, 8);
        lrow[r] = lrow[r] * f + psum;
      }
#pragma unroll
      for (int nb = 0; nb < 4; ++nb)
#pragma unroll
        for (int r = 0; r < 4; ++r) {
          oacc[nb][r] *= fscale[r];
          Ps[w][4 * g4 + r][nb * 16 + frow] = f2bf(sv[nb][r]);
        }
#pragma unroll
      for (int ks = 0; ks < 2; ++ks) {
        bf16x8 pa = *(const bf16x8*)&Ps[w][frow][ks * 32 + fk];
#pragma unroll
        for (int nb = 0; nb < 4; ++nb) {
          bf16x8 vb = *(const bf16x8*)&Vt[nb * 16 + frow][ks * 32 + fk];
          oacc[nb] = __builtin_amdgcn_mfma_f32_16x16x32_bf16(pa, vb, oacc[nb], 0, 0, 0);
        }
      }
    }

    unsigned short* yo = yout + (size_t)((size_t)b * TT + q0 + w * 16) * CCH + h * HD;
#pragma unroll
    for (int r = 0; r < 4; ++r) {
      float inv = 1.f / lrow[r];
      int row = 4 * g4 + r;
#pragma unroll
      for (int nb = 0; nb < 4; ++nb)
        yo[(size_t)row * CCH + nb * 16 + frow] = f2bf(oacc[nb][r] * inv);
    }
  }
}

// ---------------- router: fp32 LN (recomputed) + logits + top2 -------------
__global__ __launch_bounds__(256) void k_router(const float* __restrict__ x2,
    const float* __restrict__ ln2w, const float* __restrict__ rw,
    int* __restrict__ sel, float* __restrict__ selw, int* __restrict__ counts)
{
  int token = blockIdx.x * 4 + (threadIdx.x >> 6);
  int l = threadIdx.x & 63;
  const float* xr = x2 + (size_t)token * CCH;
  float xv[16];
  float s = 0.f, ss = 0.f;
#pragma unroll
  for (int j = 0; j < 16; ++j) { float v = xr[l * 16 + j]; xv[j] = v; s += v; ss += v * v; }
#pragma unroll
  for (int off = 32; off; off >>= 1) { s += __shfl_xor(s, off); ss += __shfl_xor(ss, off); }
  float mean = s * (1.f / CCH);
  float inv = rsqrtf(ss * (1.f / CCH) - mean * mean + 1e-5f);
  float logit[8] = {};
#pragma unroll
  for (int j = 0; j < 16; ++j) {
    float nv = (xv[j] - mean) * inv * ln2w[l * 16 + j];
    const float* rr = &rw[(size_t)(l * 16 + j) * EE];
#pragma unroll
    for (int e = 0; e < 8; ++e) logit[e] = fmaf(nv, rr[e], logit[e]);
  }
#pragma unroll
  for (int e = 0; e < 8; ++e) {
    float v = logit[e];
#pragma unroll
    for (int off = 32; off; off >>= 1) v += __shfl_xor(v, off);
    logit[e] = v;
  }
  float m1 = logit[0]; int i1 = 0;
#pragma unroll
  for (int e = 1; e < 8; ++e) if (logit[e] > m1) { m1 = logit[e]; i1 = e; }
  float m2 = -INFINITY; int i2 = 0;
#pragma unroll
  for (int e = 0; e < 8; ++e) if (e != i1 && logit[e] > m2) { m2 = logit[e]; i2 = e; }
  if (l == 0) {
    float w1v = 1.f / (1.f + __expf(m2 - m1));
    sel[token * 2] = i1; sel[token * 2 + 1] = i2;
    selw[token * 2] = w1v; selw[token * 2 + 1] = 1.f - w1v;
    atomicAdd(&counts[i1], 1);
    atomicAdd(&counts[i2], 1);
  }
}

__global__ void k_offsets(const int* __restrict__ counts, int* __restrict__ offs,
                          int* __restrict__ cursors) {
  if (threadIdx.x == 0 && blockIdx.x == 0) {
    int acc = 0;
    for (int e = 0; e < 8; ++e) { offs[e] = acc; cursors[e] = acc; acc += counts[e]; }
  }
}

__global__ __launch_bounds__(256) void k_scatter(const int* __restrict__ sel,
    const float* __restrict__ selw, int* __restrict__ cursors,
    int* __restrict__ tokarr, int* __restrict__ slotarr, float* __restrict__ wgtarr)
{
  int t = blockIdx.x * 256 + threadIdx.x;
  if (t >= NTOK) return;
#pragma unroll
  for (int s2 = 0; s2 < 2; ++s2) {
    int e = sel[t * 2 + s2];
    int pos = atomicAdd(&cursors[e], 1);
    tokarr[pos] = t; slotarr[pos] = s2; wgtarr[pos] = selw[t * 2 + s2];
  }
}

// ---------------- final combine: out = x2 + yp[:,0,:] + yp[:,1,:] ----------
__global__ __launch_bounds__(256) void k_combine(const float* __restrict__ x2,
    const float* __restrict__ yp, float* __restrict__ out)
{
  int i = blockIdx.x * 256 + threadIdx.x;
  int n = i >> 8, cw = i & 255;
  float4 a = ((const float4*)x2)[i];
  float4 y0 = ((const float4*)yp)[(size_t)(n * 2) * 256 + cw];
  float4 y1 = ((const float4*)yp)[(size_t)(n * 2 + 1) * 256 + cw];
  float4 o;
  o.x = a.x + y0.x + y1.x;
  o.y = a.y + y0.y + y1.y;
  o.z = a.z + y0.z + y1.z;
  o.w = a.w + y0.w + y1.w;
  ((float4*)out)[i] = o;
}

extern "C" void kernel_launch(void* const* d_in, const int* in_sizes, int n_in,
                              void* d_out, int out_size, void* d_ws, size_t ws_size,
                              hipStream_t stream) {
  const float* x     = (const float*)d_in[0];
  const float* ln1w  = (const float*)d_in[1];
  const float* attnw = (const float*)d_in[2];
  const float* projw = (const float*)d_in[3];
  const float* ln2w  = (const float*)d_in[4];
  const float* routw = (const float*)d_in[5];
  const float* w1    = (const float*)d_in[6];
  const float* w2    = (const float*)d_in[7];
  char* ws = (char*)d_ws;

  unsigned short* attn_wT = (unsigned short*)(ws + 0);          //  6,291,456
  unsigned short* proj_wT = (unsigned short*)(ws + 6291456);    //  2,097,152
  unsigned short* w1T     = (unsigned short*)(ws + 8388608);    // 33,554,432
  unsigned short* w2T     = (unsigned short*)(ws + 41943040);   // 33,554,432
  unsigned short* xn      = (unsigned short*)(ws + 75497472);   //  8,388,608
  unsigned short* qkv     = (unsigned short*)(ws + 83886080);   // 25,165,824
  unsigned short* yattn   = (unsigned short*)(ws + 109051904);  //  8,388,608
  unsigned short* hbuf    = (unsigned short*)(ws + 83886080);   // alias qkv+yattn (dead by then)
  float* x2 = (float*)(ws + 117440512);                         // 16,777,216
  float* yp = (float*)(ws + 134217728);                         // 33,554,432
  char* rbase = ws + 167772160;
  int* counts   = (int*)(rbase);
  int* cursors  = (int*)(rbase + 32);
  int* offs     = (int*)(rbase + 64);
  int* sel      = (int*)(rbase + 128);
  float* selw   = (float*)(rbase + 128 + 32768);
  int* tokarr   = (int*)(rbase + 128 + 65536);
  int* slotarr  = (int*)(rbase + 128 + 98304);
  float* wgtarr = (float*)(rbase + 128 + 131072);
  float* outp = (float*)d_out;

  hipMemsetAsync(rbase, 0, 128, stream);

  dim3 tb(32, 8);
  k_transpose<<<dim3(96, 32, 1), tb, 0, stream>>>(attnw, attn_wT, 1024, 3072);
  k_transpose<<<dim3(32, 32, 1), tb, 0, stream>>>(projw, proj_wT, 1024, 1024);
  k_transpose<<<dim3(512, 32, 1), tb, 0, stream>>>(w1, w1T, 1024, 16384);
  k_transpose<<<dim3(32, 64, 8), tb, 0, stream>>>(w2, w2T, 2048, 1024);

  k_ln<<<NTOK, 256, 0, stream>>>(x, ln1w, xn);
  // QKV: (4096 x 3072) = xn(4096x1024) @ attn_wT^T
  k_gemm128<0><<<dim3(32, 24), 256, 0, stream>>>(xn, attn_wT, qkv, nullptr, nullptr,
      NTOK, 3 * CCH, CCH, nullptr, nullptr, nullptr, nullptr, nullptr);
  k_attn_mfma<<<dim3(16, 16, 2), 256, 0, stream>>>(qkv, yattn);
  // proj + residual: x2 = x + yattn @ proj_wT^T
  k_gemm128<1><<<dim3(32, 8), 256, 0, stream>>>(yattn, proj_wT, nullptr, x2, x,
      NTOK, CCH, CCH, nullptr, nullptr, nullptr, nullptr, nullptr);
  k_ln<<<NTOK, 256, 0, stream>>>(x2, ln2w, xn);
  k_router<<<NTOK / 4, 256, 0, stream>>>(x2, ln2w, routw, sel, selw, counts);
  k_offsets<<<1, 64, 0, stream>>>(counts, offs, cursors);
  k_scatter<<<NTOK / 256, 256, 0, stream>>>(sel, selw, cursors, tokarr, slotarr, wgtarr);
  // MoE up: hbuf[off+r] = gelu(xn[tok(r)] @ w1T_e^T), N=FF, K=CCH
  k_gemm128<2><<<dim3(64, 16, 8), 256, 0, stream>>>(xn, w1T, hbuf, nullptr, nullptr,
      NTOK, FF, CCH, tokarr, slotarr, wgtarr, offs, counts);
  // MoE down: yp[tok,slot] = wgt * (hbuf[off+r] @ w2T_e^T), N=CCH, K=FF
  k_gemm128<3><<<dim3(64, 8, 8), 256, 0, stream>>>(hbuf, w2T, nullptr, yp, nullptr,
      NTOK, CCH, FF, tokarr, slotarr, wgtarr, offs, counts);
  k_combine<<<4096, 256, 0, stream>>>(x2, yp, outp);
}

// Round 5
// 711.038 us; speedup vs baseline: 1.2079x; 1.2079x over previous
//
#include <hip/hip_runtime.h>
#include <hip/hip_bf16.h>

#define BB 2
#define TT 2048
#define CCH 1024
#define HH 16
#define HD 64
#define EE 8
#define FF 2048
#define NTOK (BB*TT)

typedef __bf16 bf16x8 __attribute__((ext_vector_type(8)));
typedef float f32x4 __attribute__((ext_vector_type(4)));
typedef unsigned int u32;
typedef const u32 __attribute__((address_space(1)))* gads;
typedef u32 __attribute__((address_space(3)))* lads;

static __device__ __forceinline__ unsigned short f2bf(float f) {
  union { float f; unsigned u; } v; v.f = f;
  unsigned u = v.u;
  u += 0x7fffu + ((u >> 16) & 1u);
  return (unsigned short)(u >> 16);
}
static __device__ __forceinline__ float bf2f(unsigned short h) {
  union { unsigned u; float f; } v; v.u = ((unsigned)h) << 16;
  return v.f;
}

// ---------------- transpose fp32 (R x C) -> bf16 (C x R), batched over z ----
__global__ __launch_bounds__(256) void k_transpose(const float* __restrict__ in,
    unsigned short* __restrict__ out, int R, int Cc) {
  __shared__ float tile[32][33];
  size_t zoff = (size_t)blockIdx.z * (size_t)R * (size_t)Cc;
  int r0 = blockIdx.y * 32, c0 = blockIdx.x * 32;
  int tx = threadIdx.x, ty = threadIdx.y;
#pragma unroll
  for (int ii = 0; ii < 4; ++ii) {
    int i = ty + ii * 8;
    tile[i][tx] = in[zoff + (size_t)(r0 + i) * Cc + c0 + tx];
  }
  __syncthreads();
#pragma unroll
  for (int ii = 0; ii < 4; ++ii) {
    int i = ty + ii * 8;
    out[zoff + (size_t)(c0 + i) * R + r0 + tx] = f2bf(tile[tx][i]);
  }
}

// ---------------- layernorm row kernel: fp32 in -> bf16 out ----------------
__global__ __launch_bounds__(256) void k_ln(const float* __restrict__ x,
    const float* __restrict__ w, unsigned short* __restrict__ out) {
  int row = blockIdx.x;
  const float* xr = x + (size_t)row * CCH;
  int tid = threadIdx.x;
  float4 v = *(const float4*)&xr[tid * 4];
  float s = v.x + v.y + v.z + v.w;
  float ss = v.x * v.x + v.y * v.y + v.z * v.z + v.w * v.w;
#pragma unroll
  for (int off = 32; off; off >>= 1) { s += __shfl_xor(s, off); ss += __shfl_xor(ss, off); }
  __shared__ float red[8];
  int wv = tid >> 6, l = tid & 63;
  if (l == 0) { red[wv] = s; red[4 + wv] = ss; }
  __syncthreads();
  s = red[0] + red[1] + red[2] + red[3];
  ss = red[4] + red[5] + red[6] + red[7];
  float mean = s * (1.f / CCH);
  float var = ss * (1.f / CCH) - mean * mean;
  float inv = rsqrtf(var + 1e-5f);
  float4 w4 = *(const float4*)&w[tid * 4];
  ushort4 o;
  o.x = f2bf((v.x - mean) * inv * w4.x);
  o.y = f2bf((v.y - mean) * inv * w4.y);
  o.z = f2bf((v.z - mean) * inv * w4.z);
  o.w = f2bf((v.w - mean) * inv * w4.w);
  *(ushort4*)&out[(size_t)row * CCH + tid * 4] = o;
}

// ---------------- 128x128 GEMM: counted-vmcnt double-buffer + XOR swizzle --
// C(MxN) = A(MxK,bf16) * BT(NxK,bf16)^T, BK=64, global_load_lds width-16.
// LDS [2][128][64] per operand, linear dest; swizzle applied on the GLOBAL
// source (inverse) and the ds_read byte address (rule #21 both-sides).
// Pipeline: STAGE(buf^1) -> vmcnt(8) -> barrier -> COMPUTE(buf) -> barrier.
// vmcnt never 0 in main loop (T4).
template<int EPI>
__global__ __launch_bounds__(256, 2) void k_gemm128(
    const unsigned short* __restrict__ A, const unsigned short* __restrict__ BT,
    unsigned short* __restrict__ Cb, float* __restrict__ Cf,
    const float* __restrict__ resid, int M, int N, int K,
    const int* __restrict__ tokarr, const int* __restrict__ slotarr,
    const float* __restrict__ wgtarr, const int* __restrict__ offs,
    const int* __restrict__ counts)
{
  __shared__ __align__(16) unsigned short As[2][128 * 64];
  __shared__ __align__(16) unsigned short Bs[2][128 * 64];

  int e = 0, off = 0, cnt = M;
  if (EPI >= 2) {
    e = blockIdx.z;
    cnt = counts[e];
    off = offs[e];
    if ((int)blockIdx.x * 128 >= cnt) return;
  }
  int m0 = blockIdx.x * 128, n0 = blockIdx.y * 128;

  int tid = threadIdx.x, l = tid & 63, w = tid >> 6;
  // Staging: inst j=w*4+i covers LDS bytes [j*1024,+1024); lane l writes
  // byte j*1024+l*16 = row (j*8+(l>>3)), in-row chunk (l&7).
  // Read-side swizzle is inRow ^= (row&7)<<4, so the SOURCE chunk for
  // lane l must be (l&7) ^ ((l>>3)&7)  (row&7 == (l>>3)&7 since j*8%8==0).
  int scol = (((l & 7) ^ ((l >> 3) & 7)) * 8);
  const unsigned short* aptr[4];
  const unsigned short* bptr[4];
  const unsigned short* bbase = BT + (size_t)e * (size_t)N * K;
#pragma unroll
  for (int i = 0; i < 4; ++i) {
    int row = (w * 4 + i) * 8 + (l >> 3);
    int ra;
    if (EPI == 2)      ra = tokarr[off + min(m0 + row, cnt - 1)];
    else if (EPI == 3) ra = off + min(m0 + row, cnt - 1);
    else               ra = m0 + row;
    aptr[i] = A + (size_t)ra * K + scol;
    bptr[i] = bbase + (size_t)(n0 + row) * K + scol;
  }

  int wr = (w >> 1) * 64, wc = (w & 1) * 64;
  int frow = l & 15;
  int fkB = (l >> 4) * 16;           // byte offset of k-chunk within row
  int swz = (frow & 7) << 4;         // read-side XOR
  int inR0 = (0 + fkB) ^ swz;        // kk=0 in-row byte
  int inR1 = (64 + fkB) ^ swz;       // kk=1 in-row byte
  f32x4 acc[4][4] = {};

#define STAGE(buf, k0)                                                        \
  {                                                                           \
    _Pragma("unroll")                                                         \
    for (int i = 0; i < 4; ++i) {                                             \
      int j = w * 4 + i;                                                      \
      __builtin_amdgcn_global_load_lds((gads)(const void*)(aptr[i] + (k0)),   \
                                       (lads)(void*)&As[buf][j * 512], 16, 0, 0); \
      __builtin_amdgcn_global_load_lds((gads)(const void*)(bptr[i] + (k0)),   \
                                       (lads)(void*)&Bs[buf][j * 512], 16, 0, 0); \
    }                                                                         \
  }

#define COMPUTE(buf)                                                          \
  {                                                                           \
    const char* abase = (const char*)&As[buf][0];                             \
    const char* bbse  = (const char*)&Bs[buf][0];                             \
    _Pragma("unroll")                                                         \
    for (int kk = 0; kk < 2; ++kk) {                                          \
      int inr = kk ? inR1 : inR0;                                             \
      bf16x8 af[4], bfr[4];                                                   \
      _Pragma("unroll")                                                       \
      for (int mi = 0; mi < 4; ++mi)                                          \
        af[mi] = *(const bf16x8*)(abase + (wr + mi * 16 + frow) * 128 + inr); \
      _Pragma("unroll")                                                       \
      for (int ni = 0; ni < 4; ++ni)                                          \
        bfr[ni] = *(const bf16x8*)(bbse + (wc + ni * 16 + frow) * 128 + inr); \
      _Pragma("unroll")                                                       \
      for (int mi = 0; mi < 4; ++mi)                                          \
        _Pragma("unroll")                                                     \
        for (int ni = 0; ni < 4; ++ni)                                        \
          acc[mi][ni] = __builtin_amdgcn_mfma_f32_16x16x32_bf16(af[mi], bfr[ni], \
                                                                acc[mi][ni], 0, 0, 0); \
    }                                                                         \
  }

#define VMW8  asm volatile("s_waitcnt vmcnt(8)" ::: "memory")
#define VMW0  asm volatile("s_waitcnt vmcnt(0)" ::: "memory")
#define FENCE asm volatile("" ::: "memory")
#define BAR   __builtin_amdgcn_s_barrier()

  int nt = K / 64;  // 16 or 32, always even
  STAGE(0, 0);
  for (int t = 0; t + 2 < nt; t += 2) {
    STAGE(1, (t + 1) * 64);
    VMW8; BAR;
    COMPUTE(0);
    FENCE; BAR;
    STAGE(0, (t + 2) * 64);
    VMW8; BAR;
    COMPUTE(1);
    FENCE; BAR;
  }
  STAGE(1, (nt - 1) * 64);
  VMW8; BAR;
  COMPUTE(0);
  FENCE; BAR;
  VMW0; BAR;
  COMPUTE(1);

#undef STAGE
#undef COMPUTE
#undef VMW8
#undef VMW0
#undef FENCE
#undef BAR

  int g4 = (l >> 4) * 4, cl = l & 15;
#pragma unroll
  for (int mi = 0; mi < 4; ++mi) {
#pragma unroll
    for (int r = 0; r < 4; ++r) {
      int grow = m0 + wr + mi * 16 + g4 + r;
      if (EPI >= 2 && grow >= cnt) continue;
      int tok = 0, slot = 0; float wg = 0.f;
      if (EPI == 3) {
        int fl = off + grow;
        tok = tokarr[fl]; slot = slotarr[fl]; wg = wgtarr[fl];
      }
#pragma unroll
      for (int ni = 0; ni < 4; ++ni) {
        int gcol = n0 + wc + ni * 16 + cl;
        float v = acc[mi][ni][r];
        if (EPI == 0) {
          Cb[(size_t)grow * N + gcol] = f2bf(v);
        } else if (EPI == 1) {
          Cf[(size_t)grow * N + gcol] = v + resid[(size_t)grow * N + gcol];
        } else if (EPI == 2) {
          float g = 0.5f * v * (1.f + erff(v * 0.70710678118654752f));
          Cb[(size_t)(off + grow) * N + gcol] = f2bf(g);
        } else {
          Cf[((size_t)tok * 2 + slot) * N + gcol] = wg * v;
        }
      }
    }
  }
}

// ---------------- MFMA flash attention ------------------------------------
__global__ __launch_bounds__(256) void k_attn_mfma(const unsigned short* __restrict__ qkv,
    unsigned short* __restrict__ yout)
{
  int bx = blockIdx.x, h = blockIdx.y, b = blockIdx.z;
  int tid = threadIdx.x, l = tid & 63, w = tid >> 6;
  const size_t rs = 3 * CCH;
  const int NTILE = TT / 64;  // 32

  __shared__ __align__(16) unsigned short Ks[64][72];
  __shared__ __align__(16) unsigned short Vt[64][72];
  __shared__ __align__(16) unsigned short Ps[4][16][72];

  int frow = l & 15, fk = (l >> 4) * 8;
  int g4 = l >> 4;
  int kr = tid >> 2, kc0 = (tid & 3) * 8;
  int vr = tid >> 2, vc0 = (tid & 3) * 16;

  for (int half = 0; half < 2; ++half) {
    int qt = half ? (NTILE - 1 - bx) : bx;
    int q0 = qt * 64;

    const unsigned short* qp = qkv + (size_t)((size_t)b * TT + q0 + w * 16 + frow) * rs + h * HD;
    bf16x8 qf0 = *(const bf16x8*)&qp[fk];
    bf16x8 qf1 = *(const bf16x8*)&qp[32 + fk];

    f32x4 oacc[4] = {};
    float mrow[4] = {-INFINITY, -INFINITY, -INFINITY, -INFINITY};
    float lrow[4] = {};

    for (int kb = 0; kb <= qt; ++kb) {
      int k0 = kb * 64;
      __syncthreads();
      const unsigned short* kp = qkv + (size_t)((size_t)b * TT + k0 + kr) * rs + CCH + h * HD;
      *(uint4*)&Ks[kr][kc0]      = *(const uint4*)&kp[kc0];
      *(uint4*)&Ks[kr][kc0 + 32] = *(const uint4*)&kp[kc0 + 32];
      const unsigned short* vp = qkv + (size_t)((size_t)b * TT + k0 + vr) * rs + 2 * CCH + h * HD + vc0;
      uint4 v0 = *(const uint4*)&vp[0];
      uint4 v1 = *(const uint4*)&vp[8];
      unsigned short tmp[16];
      *(uint4*)&tmp[0] = v0; *(uint4*)&tmp[8] = v1;
#pragma unroll
      for (int j = 0; j < 16; ++j) Vt[vc0 + j][vr] = tmp[j];
      __syncthreads();

      f32x4 sacc[4] = {};
#pragma unroll
      for (int nb = 0; nb < 4; ++nb) {
        bf16x8 kf0 = *(const bf16x8*)&Ks[nb * 16 + frow][fk];
        bf16x8 kf1 = *(const bf16x8*)&Ks[nb * 16 + frow][32 + fk];
        sacc[nb] = __builtin_amdgcn_mfma_f32_16x16x32_bf16(qf0, kf0, sacc[nb], 0, 0, 0);
        sacc[nb] = __builtin_amdgcn_mfma_f32_16x16x32_bf16(qf1, kf1, sacc[nb], 0, 0, 0);
      }

      bool diag = (kb == qt);
      float sv[4][4];
#pragma unroll
      for (int nb = 0; nb < 4; ++nb)
#pragma unroll
        for (int r = 0; r < 4; ++r) {
          float v = sacc[nb][r] * 0.125f;
          if (diag) {
            int ckv = nb * 16 + frow;
            int rq = w * 16 + 4 * g4 + r;
            if (ckv > rq) v = -INFINITY;
          }
          sv[nb][r] = v;
        }
      float fscale[4];
#pragma unroll
      for (int r = 0; r < 4; ++r) {
        float vm = fmaxf(fmaxf(sv[0][r], sv[1][r]), fmaxf(sv[2][r], sv[3][r]));
        vm = fmaxf(vm, __shfl_xor(vm, 1));
        vm = fmaxf(vm, __shfl_xor(vm, 2));
        vm = fmaxf(vm, __shfl_xor(vm, 4));
        vm = fmaxf(vm, __shfl_xor(vm, 8));
        float mnew = fmaxf(mrow[r], vm);
        float f = __expf(mrow[r] - mnew);
        mrow[r] = mnew;
        fscale[r] = f;
        float psum = 0.f;
#pragma unroll
        for (int nb = 0; nb < 4; ++nb) {
          float p = __expf(sv[nb][r] - mnew);
          sv[nb][r] = p;
          psum += p;
        }
        psum += __shfl_xor(psum, 1);
        psum += __shfl_xor(psum, 2);
        psum += __shfl_xor(psum, 4);
        psum += __shfl_xor(psum, 8);
        lrow[r] = lrow[r] * f + psum;
      }
#pragma unroll
      for (int nb = 0; nb < 4; ++nb)
#pragma unroll
        for (int r = 0; r < 4; ++r) {
          oacc[nb][r] *= fscale[r];
          Ps[w][4 * g4 + r][nb * 16 + frow] = f2bf(sv[nb][r]);
        }
#pragma unroll
      for (int ks = 0; ks < 2; ++ks) {
        bf16x8 pa = *(const bf16x8*)&Ps[w][frow][ks * 32 + fk];
#pragma unroll
        for (int nb = 0; nb < 4; ++nb) {
          bf16x8 vb = *(const bf16x8*)&Vt[nb * 16 + frow][ks * 32 + fk];
          oacc[nb] = __builtin_amdgcn_mfma_f32_16x16x32_bf16(pa, vb, oacc[nb], 0, 0, 0);
        }
      }
    }

    unsigned short* yo = yout + (size_t)((size_t)b * TT + q0 + w * 16) * CCH + h * HD;
#pragma unroll
    for (int r = 0; r < 4; ++r) {
      float inv = 1.f / lrow[r];
      int row = 4 * g4 + r;
#pragma unroll
      for (int nb = 0; nb < 4; ++nb)
        yo[(size_t)row * CCH + nb * 16 + frow] = f2bf(oacc[nb][r] * inv);
    }
  }
}

// ---------------- router: fp32 LN (recomputed) + logits + top2 -------------
__global__ __launch_bounds__(256) void k_router(const float* __restrict__ x2,
    const float* __restrict__ ln2w, const float* __restrict__ rw,
    int* __restrict__ sel, float* __restrict__ selw, int* __restrict__ counts)
{
  int token = blockIdx.x * 4 + (threadIdx.x >> 6);
  int l = threadIdx.x & 63;
  const float* xr = x2 + (size_t)token * CCH;
  float xv[16];
  float s = 0.f, ss = 0.f;
#pragma unroll
  for (int j = 0; j < 16; ++j) { float v = xr[l * 16 + j]; xv[j] = v; s += v; ss += v * v; }
#pragma unroll
  for (int off = 32; off; off >>= 1) { s += __shfl_xor(s, off); ss += __shfl_xor(ss, off); }
  float mean = s * (1.f / CCH);
  float inv = rsqrtf(ss * (1.f / CCH) - mean * mean + 1e-5f);
  float logit[8] = {};
#pragma unroll
  for (int j = 0; j < 16; ++j) {
    float nv = (xv[j] - mean) * inv * ln2w[l * 16 + j];
    const float* rr = &rw[(size_t)(l * 16 + j) * EE];
#pragma unroll
    for (int e = 0; e < 8; ++e) logit[e] = fmaf(nv, rr[e], logit[e]);
  }
#pragma unroll
  for (int e = 0; e < 8; ++e) {
    float v = logit[e];
#pragma unroll
    for (int off = 32; off; off >>= 1) v += __shfl_xor(v, off);
    logit[e] = v;
  }
  float m1 = logit[0]; int i1 = 0;
#pragma unroll
  for (int e = 1; e < 8; ++e) if (logit[e] > m1) { m1 = logit[e]; i1 = e; }
  float m2 = -INFINITY; int i2 = 0;
#pragma unroll
  for (int e = 0; e < 8; ++e) if (e != i1 && logit[e] > m2) { m2 = logit[e]; i2 = e; }
  if (l == 0) {
    float w1v = 1.f / (1.f + __expf(m2 - m1));
    sel[token * 2] = i1; sel[token * 2 + 1] = i2;
    selw[token * 2] = w1v; selw[token * 2 + 1] = 1.f - w1v;
    atomicAdd(&counts[i1], 1);
    atomicAdd(&counts[i2], 1);
  }
}

__global__ void k_offsets(const int* __restrict__ counts, int* __restrict__ offs,
                          int* __restrict__ cursors) {
  if (threadIdx.x == 0 && blockIdx.x == 0) {
    int acc = 0;
    for (int e = 0; e < 8; ++e) { offs[e] = acc; cursors[e] = acc; acc += counts[e]; }
  }
}

__global__ __launch_bounds__(256) void k_scatter(const int* __restrict__ sel,
    const float* __restrict__ selw, int* __restrict__ cursors,
    int* __restrict__ tokarr, int* __restrict__ slotarr, float* __restrict__ wgtarr)
{
  int t = blockIdx.x * 256 + threadIdx.x;
  if (t >= NTOK) return;
#pragma unroll
  for (int s2 = 0; s2 < 2; ++s2) {
    int e = sel[t * 2 + s2];
    int pos = atomicAdd(&cursors[e], 1);
    tokarr[pos] = t; slotarr[pos] = s2; wgtarr[pos] = selw[t * 2 + s2];
  }
}

// ---------------- final combine: out = x2 + yp[:,0,:] + yp[:,1,:] ----------
__global__ __launch_bounds__(256) void k_combine(const float* __restrict__ x2,
    const float* __restrict__ yp, float* __restrict__ out)
{
  int i = blockIdx.x * 256 + threadIdx.x;
  int n = i >> 8, cw = i & 255;
  float4 a = ((const float4*)x2)[i];
  float4 y0 = ((const float4*)yp)[(size_t)(n * 2) * 256 + cw];
  float4 y1 = ((const float4*)yp)[(size_t)(n * 2 + 1) * 256 + cw];
  float4 o;
  o.x = a.x + y0.x + y1.x;
  o.y = a.y + y0.y + y1.y;
  o.z = a.z + y0.z + y1.z;
  o.w = a.w + y0.w + y1.w;
  ((float4*)out)[i] = o;
}

extern "C" void kernel_launch(void* const* d_in, const int* in_sizes, int n_in,
                              void* d_out, int out_size, void* d_ws, size_t ws_size,
                              hipStream_t stream) {
  const float* x     = (const float*)d_in[0];
  const float* ln1w  = (const float*)d_in[1];
  const float* attnw = (const float*)d_in[2];
  const float* projw = (const float*)d_in[3];
  const float* ln2w  = (const float*)d_in[4];
  const float* routw = (const float*)d_in[5];
  const float* w1    = (const float*)d_in[6];
  const float* w2    = (const float*)d_in[7];
  char* ws = (char*)d_ws;

  unsigned short* attn_wT = (unsigned short*)(ws + 0);          //  6,291,456
  unsigned short* proj_wT = (unsigned short*)(ws + 6291456);    //  2,097,152
  unsigned short* w1T     = (unsigned short*)(ws + 8388608);    // 33,554,432
  unsigned short* w2T     = (unsigned short*)(ws + 41943040);   // 33,554,432
  unsigned short* xn      = (unsigned short*)(ws + 75497472);   //  8,388,608
  unsigned short* qkv     = (unsigned short*)(ws + 83886080);   // 25,165,824
  unsigned short* yattn   = (unsigned short*)(ws + 109051904);  //  8,388,608
  unsigned short* hbuf    = (unsigned short*)(ws + 83886080);   // alias qkv+yattn (dead by then)
  float* x2 = (float*)(ws + 117440512);                         // 16,777,216
  float* yp = (float*)(ws + 134217728);                         // 33,554,432
  char* rbase = ws + 167772160;
  int* counts   = (int*)(rbase);
  int* cursors  = (int*)(rbase + 32);
  int* offs     = (int*)(rbase + 64);
  int* sel      = (int*)(rbase + 128);
  float* selw   = (float*)(rbase + 128 + 32768);
  int* tokarr   = (int*)(rbase + 128 + 65536);
  int* slotarr  = (int*)(rbase + 128 + 98304);
  float* wgtarr = (float*)(rbase + 128 + 131072);
  float* outp = (float*)d_out;

  hipMemsetAsync(rbase, 0, 128, stream);

  dim3 tb(32, 8);
  k_transpose<<<dim3(96, 32, 1), tb, 0, stream>>>(attnw, attn_wT, 1024, 3072);
  k_transpose<<<dim3(32, 32, 1), tb, 0, stream>>>(projw, proj_wT, 1024, 1024);
  k_transpose<<<dim3(512, 32, 1), tb, 0, stream>>>(w1, w1T, 1024, 16384);
  k_transpose<<<dim3(32, 64, 8), tb, 0, stream>>>(w2, w2T, 2048, 1024);

  k_ln<<<NTOK, 256, 0, stream>>>(x, ln1w, xn);
  // QKV: (4096 x 3072) = xn(4096x1024) @ attn_wT^T
  k_gemm128<0><<<dim3(32, 24), 256, 0, stream>>>(xn, attn_wT, qkv, nullptr, nullptr,
      NTOK, 3 * CCH, CCH, nullptr, nullptr, nullptr, nullptr, nullptr);
  k_attn_mfma<<<dim3(16, 16, 2), 256, 0, stream>>>(qkv, yattn);
  // proj + residual: x2 = x + yattn @ proj_wT^T
  k_gemm128<1><<<dim3(32, 8), 256, 0, stream>>>(yattn, proj_wT, nullptr, x2, x,
      NTOK, CCH, CCH, nullptr, nullptr, nullptr, nullptr, nullptr);
  k_ln<<<NTOK, 256, 0, stream>>>(x2, ln2w, xn);
  k_router<<<NTOK / 4, 256, 0, stream>>>(x2, ln2w, routw, sel, selw, counts);
  k_offsets<<<1, 64, 0, stream>>>(counts, offs, cursors);
  k_scatter<<<NTOK / 256, 256, 0, stream>>>(sel, selw, cursors, tokarr, slotarr, wgtarr);
  // MoE up: hbuf[off+r] = gelu(xn[tok(r)] @ w1T_e^T), N=FF, K=CCH
  k_gemm128<2><<<dim3(32, 16, 8), 256, 0, stream>>>(xn, w1T, hbuf, nullptr, nullptr,
      NTOK, FF, CCH, tokarr, slotarr, wgtarr, offs, counts);
  // MoE down: yp[tok,slot] = wgt * (hbuf[off+r] @ w2T_e^T), N=CCH, K=FF
  k_gemm128<3><<<dim3(32, 8, 8), 256, 0, stream>>>(hbuf, w2T, nullptr, yp, nullptr,
      NTOK, CCH, FF, tokarr, slotarr, wgtarr, offs, counts);
  k_combine<<<4096, 256, 0, stream>>>(x2, yp, outp);
}